// Round 1
// baseline (780.760 us; speedup 1.0000x reference)
//
#include <hip/hip_runtime.h>

#define TT 512
#define DD 64
#define BB 1024
#define PF 8               // prefetch depth (steps) in the recurrence
#define HH 8

typedef float v2f __attribute__((ext_vector_type(2)));

__device__ __forceinline__ float fexp2(float x){ return __builtin_amdgcn_exp2f(x); }
__device__ __forceinline__ float frcp (float x){ return __builtin_amdgcn_rcpf(x); }

__device__ __forceinline__ v2f bc2(float s){ v2f r; r.x = s; r.y = s; return r; }

#if defined(__has_builtin)
#if __has_builtin(__builtin_elementwise_fma)
#define HAVE_EW_FMA 1
#endif
#endif

__device__ __forceinline__ v2f vfma(v2f a, v2f b, v2f c){
#ifdef HAVE_EW_FMA
  return __builtin_elementwise_fma(a, b, c);
#else
  v2f r; r.x = fmaf(a.x, b.x, c.x); r.y = fmaf(a.y, b.y, c.y); return r;
#endif
}

// DPP: quad_perm uniform selectors (direction-proof) and row_ror:4k whose
// direction is resolved by a runtime probe.
template<int C>
__device__ __forceinline__ float dppf(float x){
  return __int_as_float(__builtin_amdgcn_update_dpp(0, __float_as_int(x), C, 0xF, 0xF, true));
}
template<int C>
__device__ __forceinline__ int dppi(int x){
  return __builtin_amdgcn_update_dpp(0, x, C, 0xF, 0xF, true);
}

template<int N> struct IC { static constexpr int v = N; };

// ============================================================
// Kernel 1 (v3): layer-0 input projection for both phases.
// P[ph][e][t][32], pos(r) = (gate*4 + (j&3))*2 + (j>>2), value includes bias.
// 2048 blocks x 256 threads. Each wave owns 64 consecutive x-rows.
// Key change vs v2: the broadcast operand (the x-row) is WAVE-UNIFORM, so it
// is loaded via the SCALAR path (s_load) instead of staged through LDS and
// ds_read_b128-broadcast. Per row: ~4 s_load_dwordx16 + 64 v_fmac(s,v).
// Zero LDS, zero staging VGPRs, no barriers.
//   - lane c in [0,64): c<32 -> encoder gate-row c; c>=32 -> decoder row c-32
//   - Wx[64] per lane (VGPR), x-row elements broadcast from SGPRs
// ============================================================
__global__ __launch_bounds__(256) void proj_kernel(
    const float* __restrict__ x,
    const float* __restrict__ eWih0, const float* __restrict__ eBih, const float* __restrict__ eBhh,
    const float* __restrict__ dWih0, const float* __restrict__ dBih, const float* __restrict__ dBhh,
    float* __restrict__ P)
{
  const int tid  = threadIdx.x;
  // readfirstlane: make the wave id uniform for the compiler's uniformity
  // analysis so x-row loads scalarize to s_load (SMEM path).
  const int w    = __builtin_amdgcn_readfirstlane(tid >> 6);
  const int lane = tid & 63;
  const int ph   = lane >> 5;
  const int r    = lane & 31;
  const float* W = ph ? dWih0 : eWih0;
  const float b0 = ph ? (dBih[r] + dBhh[r]) : (eBih[r] + eBhh[r]);
  const int gate = r >> 3, j = r & 7;
  const int pos  = (gate * 4 + (j & 3)) * 2 + (j >> 2);

  float Wx[64];
#pragma unroll
  for (int k = 0; k < 16; ++k) {
    float4 wq = *(const float4*)(W + r * 64 + k * 4);
    Wx[k*4+0] = wq.x; Wx[k*4+1] = wq.y; Wx[k*4+2] = wq.z; Wx[k*4+3] = wq.w;
  }

  const int base_row = (blockIdx.x * 4 + w) * 64;     // 8192 waves x 64 rows
  const float* xg = x + (size_t)base_row * 64;
  // whole 64-row chunk lies inside one e-block (64 | 512)
  const int e  = base_row >> 9;
  const int t0 = base_row & 511;
  float* Pout = P + ((size_t)((ph << 10) + e) * TT + t0) * 32 + pos;

#pragma unroll 2
  for (int ri = 0; ri < 64; ++ri) {
    const float* xr = xg + ri * 64;   // wave-uniform pointer -> scalar loads
    float a0 = b0, a1 = 0.f, a2 = 0.f, a3 = 0.f;
#pragma unroll
    for (int kc = 0; kc < 16; ++kc) {
      float4 xv = *(const float4*)(xr + kc * 4);      // uniform -> s_load
      a0 = fmaf(Wx[kc*4+0], xv.x, a0);
      a1 = fmaf(Wx[kc*4+1], xv.y, a1);
      a2 = fmaf(Wx[kc*4+2], xv.z, a2);
      a3 = fmaf(Wx[kc*4+3], xv.w, a3);
    }
    Pout[(size_t)ri * 32] = (a0 + a1) + (a2 + a3);
  }
}

// ============================================================
// Kernel 2: recurrence (UNCHANGED — verified absmax 0.0).
// 256 blocks x 64 threads; each wave = 4 batch elements, 16 lanes each
// (u = L>>2 unit-quad, g = L&3 torch gate). Slot pair (u, u+4) packed in v2f.
// No LDS, no barriers; P prefetched PF steps ahead in registers.
// ============================================================
__global__ __launch_bounds__(64) void recur_kernel(
    const float* __restrict__ P,
    const float* __restrict__ h0,    const float* __restrict__ c0,
    const float* __restrict__ eWihR, const float* __restrict__ eWhh,
    const float* __restrict__ eBih,  const float* __restrict__ eBhh,
    const float* __restrict__ dWihR, const float* __restrict__ dWhh,
    const float* __restrict__ dBih,  const float* __restrict__ dBhh,
    const float* __restrict__ linW,  const float* __restrict__ linB,
    float* __restrict__ out)
{
  const int lane = threadIdx.x;
  const int row  = lane >> 4;
  const int L    = lane & 15;
  const int u    = L >> 2;
  const int g    = L & 3;
  const int e    = blockIdx.x * 4 + row;

  const bool is_tanh = (g == 2);
  const float ns_act = is_tanh ? -2.885390082f : -1.44269504f;
  const float a_act  = is_tanh ? 2.0f : 1.0f;
  const float b_act  = is_tanh ? -1.0f : 0.0f;

  // runtime direction probe for row_ror:4 (wave-uniform d = 1 or 3)
  const int p4 = dppi<0x124>(u);
  const int d  = __builtin_amdgcn_readfirstlane((p4 - u) & 3);

  v2f H[3], cs[3], sd[3];
  v2f bd1 = bc2(0.f), bd2 = bc2(0.f);
  v2f WS[3][8], WB[2][8], Bss[2];

#pragma unroll
  for (int l = 0; l < 3; ++l) {
    H[l].x  = h0[((size_t)l * BB + e) * HH + u];
    H[l].y  = h0[((size_t)l * BB + e) * HH + u + 4];
    cs[l].x = c0[((size_t)l * BB + e) * HH + u];
    cs[l].y = c0[((size_t)l * BB + e) * HH + u + 4];
  }

  auto load_phase = [&](const float* WihR, const float* Whh,
                        const float* Bih, const float* Bhh) {
#pragma unroll
    for (int l = 0; l < 3; ++l) {
      const int r0 = l * 32 + g * 8 + u;
#pragma unroll
      for (int k = 0; k < 4; ++k) {
        const int col = (u + d * k) & 3;
        WS[l][k].x     = Whh[r0 * 8 + col];
        WS[l][k].y     = Whh[(r0 + 4) * 8 + col];
        WS[l][4 + k].x = Whh[r0 * 8 + 4 + col];
        WS[l][4 + k].y = Whh[(r0 + 4) * 8 + 4 + col];
      }
    }
#pragma unroll
    for (int l = 0; l < 2; ++l) {
      const int r0 = l * 32 + g * 8 + u;
#pragma unroll
      for (int k = 0; k < 4; ++k) {
        const int col = (u + d * k) & 3;
        WB[l][k].x     = WihR[r0 * 8 + col];
        WB[l][k].y     = WihR[(r0 + 4) * 8 + col];
        WB[l][4 + k].x = WihR[r0 * 8 + 4 + col];
        WB[l][4 + k].y = WihR[(r0 + 4) * 8 + 4 + col];
      }
      Bss[l].x = Bih[(l + 1) * 32 + g * 8 + u]     + Bhh[(l + 1) * 32 + g * 8 + u];
      Bss[l].y = Bih[(l + 1) * 32 + g * 8 + u + 4] + Bhh[(l + 1) * 32 + g * 8 + u + 4];
    }
    // self-dots from current h (layer-0 bias lives inside P)
#pragma unroll
    for (int l = 0; l < 3; ++l) {
      float A0[4], B0[4];
      A0[0] = H[l].x; A0[1] = dppf<0x124>(H[l].x); A0[2] = dppf<0x128>(H[l].x); A0[3] = dppf<0x12C>(H[l].x);
      B0[0] = H[l].y; B0[1] = dppf<0x124>(H[l].y); B0[2] = dppf<0x128>(H[l].y); B0[3] = dppf<0x12C>(H[l].y);
      v2f acc = bc2(0.f);
      if (l) acc = Bss[l - 1];
#pragma unroll
      for (int k = 0; k < 4; ++k) {
        acc = vfma(WS[l][k],     bc2(A0[k]), acc);
        acc = vfma(WS[l][4 + k], bc2(B0[k]), acc);
      }
      sd[l] = acc;
    }
  };

  // one packed LSTM cell step for layer l; returns below-dot for layer l+1
  auto lstep = [&](auto LC, v2f in) -> v2f {
    constexpr int l = decltype(LC)::v;
    v2f pre = in + sd[l];
    v2f ex; ex.x = fexp2(ns_act * pre.x); ex.y = fexp2(ns_act * pre.y);
    v2f rc; rc.x = frcp(1.f + ex.x);      rc.y = frcp(1.f + ex.y);
    v2f act = vfma(bc2(a_act), rc, bc2(b_act));
    v2f Gi, Gf, Gg, Go;
    Gi.x = dppf<0x00>(act.x); Gi.y = dppf<0x00>(act.y);
    Gf.x = dppf<0x55>(act.x); Gf.y = dppf<0x55>(act.y);
    Gg.x = dppf<0xAA>(act.x); Gg.y = dppf<0xAA>(act.y);
    Go.x = dppf<0xFF>(act.x); Go.y = dppf<0xFF>(act.y);
    v2f cn = vfma(Gf, cs[l], Gi * Gg);
    cs[l] = cn;
    v2f tx; tx.x = fexp2(-2.885390082f * cn.x); tx.y = fexp2(-2.885390082f * cn.y);
    v2f tr; tr.x = frcp(1.f + tx.x);            tr.y = frcp(1.f + tx.y);
    v2f th = vfma(bc2(2.f), tr, bc2(-1.f));
    v2f hn = Go * th;
    H[l] = hn;
    float A0[4], B0[4];
    A0[0] = hn.x; A0[1] = dppf<0x124>(hn.x); A0[2] = dppf<0x128>(hn.x); A0[3] = dppf<0x12C>(hn.x);
    B0[0] = hn.y; B0[1] = dppf<0x124>(hn.y); B0[2] = dppf<0x128>(hn.y); B0[3] = dppf<0x12C>(hn.y);
    v2f accS;
    if constexpr (l > 0) accS = Bss[l - 1]; else accS = bc2(0.f);
    v2f accB = bc2(0.f);
#pragma unroll
    for (int k = 0; k < 4; ++k) {
      accS = vfma(WS[l][k],     bc2(A0[k]), accS);
      accS = vfma(WS[l][4 + k], bc2(B0[k]), accS);
      if constexpr (l < 2) {
        accB = vfma(WB[l][k],     bc2(A0[k]), accB);
        accB = vfma(WB[l][4 + k], bc2(B0[k]), accB);
      }
    }
    sd[l] = accS;
    return accB;
  };

#pragma unroll 1
  for (int ph = 0; ph < 2; ++ph) {
    if (ph == 0) load_phase(eWihR, eWhh, eBih, eBhh);
    else         load_phase(dWihR, dWhh, dBih, dBhh);

    const float* Pb = P + ((size_t)((ph << 10) + e) * TT) * 32 + (g * 4 + u) * 2;

    // fill prefetch pipeline with steps 0..PF-1
    v2f pf[PF];
#pragma unroll
    for (int k = 0; k < PF; ++k) pf[k] = *(const v2f*)(Pb + k * 32);

    // peeled group t = 0..7 (skew startup), refill t = 8..15
#pragma unroll
    for (int k = 0; k < PF; ++k) {
      v2f cur = pf[k];
      pf[k] = *(const v2f*)(Pb + (k + PF) * 32);
      v2f n1 = lstep(IC<0>{}, cur);
      v2f n2 = bc2(0.f);
      if (k >= 1) n2 = lstep(IC<1>{}, bd1);
      if (k >= 2) (void)lstep(IC<2>{}, bd2);
      bd1 = n1; bd2 = n2;
    }

    // main loop t = 8..511, branch-free
#pragma unroll 1
    for (int t = PF; t < TT; t += PF) {
#pragma unroll
      for (int k = 0; k < PF; ++k) {
        v2f cur = pf[k];
        int tn = t + k + PF; if (tn > TT - 1) tn = TT - 1;
        pf[k] = *(const v2f*)(Pb + tn * 32);
        v2f n1 = lstep(IC<0>{}, cur);
        v2f n2 = lstep(IC<1>{}, bd1);
        (void)lstep(IC<2>{}, bd2);
        bd1 = n1; bd2 = n2;
      }
    }

    // drain skew: layer1 t=511, layer2 t=510, layer2 t=511
    v2f dd = lstep(IC<1>{}, bd1);
    (void)lstep(IC<2>{}, bd2);
    (void)lstep(IC<2>{}, dd);
  }

  // epilogue: linear on final decoder layer-2 h
  float lwA[4], lwB[4];
#pragma unroll
  for (int k = 0; k < 4; ++k) {
    const int col = (u + d * k) & 3;
    lwA[k] = linW[col];
    lwB[k] = linW[4 + col];
  }
  float A0[4], B0[4];
  A0[0] = H[2].x; A0[1] = dppf<0x124>(H[2].x); A0[2] = dppf<0x128>(H[2].x); A0[3] = dppf<0x12C>(H[2].x);
  B0[0] = H[2].y; B0[1] = dppf<0x124>(H[2].y); B0[2] = dppf<0x128>(H[2].y); B0[3] = dppf<0x12C>(H[2].y);
  float pred = linB[0];
#pragma unroll
  for (int k = 0; k < 4; ++k) {
    pred = fmaf(lwA[k], A0[k], pred);
    pred = fmaf(lwB[k], B0[k], pred);
  }
  if (L == 0) out[e] = pred;
}

// ============================================================
// Fallback (ws too small): round-1 verified single-kernel version.
// ============================================================
__global__ __launch_bounds__(64) void seq2seq_fallback(
    const float* __restrict__ x, const float* __restrict__ h0, const float* __restrict__ c0,
    const float* __restrict__ eWih0, const float* __restrict__ eWihR, const float* __restrict__ eWhh,
    const float* __restrict__ eBih,  const float* __restrict__ eBhh,
    const float* __restrict__ dWih0, const float* __restrict__ dWihR, const float* __restrict__ dWhh,
    const float* __restrict__ dBih,  const float* __restrict__ dBhh,
    const float* __restrict__ linW,  const float* __restrict__ linB, float* __restrict__ out)
{
  const int tid = threadIdx.x;
  const int g   = tid & 31;
  const int grp = tid & 32;
  const int jj  = g & 7;
  const int e   = blockIdx.x * 2 + (tid >> 5);
  const bool is_tanh = ((g >> 3) == 2);
  const float s_act = is_tanh ? 2.885390082f : 1.44269504f;
  const float a_act = is_tanh ? 2.0f : 1.0f;
  const float b_act = is_tanh ? -1.0f : 0.0f;
  float hrep[3][8]; float cc[3];
#pragma unroll
  for (int l = 0; l < 3; ++l) {
#pragma unroll
    for (int k = 0; k < 8; ++k) hrep[l][k] = h0[((size_t)l * BB + e) * HH + k];
    cc[l] = c0[((size_t)l * BB + e) * HH + jj];
  }
  for (int p = 0; p < 2; ++p) {
    const float* Wih0 = p ? dWih0 : eWih0;  const float* WihR = p ? dWihR : eWihR;
    const float* Whh  = p ? dWhh  : eWhh;   const float* Bih  = p ? dBih  : eBih;
    const float* Bhh  = p ? dBhh  : eBhh;
    float Wx[64];
#pragma unroll
    for (int k = 0; k < 64; k += 4) {
      float4 w = *(const float4*)(Wih0 + g * 64 + k);
      Wx[k] = w.x; Wx[k+1] = w.y; Wx[k+2] = w.z; Wx[k+3] = w.w;
    }
    float Wh[3][8], Wi[2][8], bias[3];
#pragma unroll
    for (int l = 0; l < 3; ++l) {
#pragma unroll
      for (int k = 0; k < 8; ++k) Wh[l][k] = Whh[(l*32+g)*8+k];
      bias[l] = Bih[l*32+g] + Bhh[l*32+g];
    }
#pragma unroll
    for (int l = 0; l < 2; ++l)
#pragma unroll
      for (int k = 0; k < 8; ++k) Wi[l][k] = WihR[(l*32+g)*8+k];
    const float* xrow = x + (size_t)e * TT * DD;
    for (int t = 0; t < TT; ++t) {
      float4 acc = make_float4(bias[0], 0.f, 0.f, 0.f);
#pragma unroll
      for (int kc = 0; kc < 16; ++kc) {
        float4 xv = *(const float4*)(xrow + kc * 4);
        acc.x = fmaf(Wx[kc*4+0], xv.x, acc.x); acc.y = fmaf(Wx[kc*4+1], xv.y, acc.y);
        acc.z = fmaf(Wx[kc*4+2], xv.z, acc.z); acc.w = fmaf(Wx[kc*4+3], xv.w, acc.w);
      }
      float pre = (acc.x + acc.y) + (acc.z + acc.w);
      { float r0=0.f,r1=0.f;
#pragma unroll
        for (int k = 0; k < 8; k += 2) { r0=fmaf(Wh[0][k],hrep[0][k],r0); r1=fmaf(Wh[0][k+1],hrep[0][k+1],r1); }
        pre += r0 + r1; }
#pragma unroll
      for (int l = 0; l < 3; ++l) {
        if (l > 0) {
          float r0 = bias[l], r1 = 0.f;
#pragma unroll
          for (int k = 0; k < 8; k += 2) {
            r0=fmaf(Wi[l-1][k],hrep[l-1][k],r0); r1=fmaf(Wi[l-1][k+1],hrep[l-1][k+1],r1);
            r0=fmaf(Wh[l][k],hrep[l][k],r0);     r1=fmaf(Wh[l][k+1],hrep[l][k+1],r1);
          }
          pre = r0 + r1;
        }
        float act = fmaf(a_act, frcp(1.0f + fexp2(-s_act * pre)), b_act);
        float iv = __shfl(act, grp + jj);
        float fv = __shfl(act, grp + 8 + jj);
        float gv = __shfl(act, grp + 16 + jj);
        float ov = __shfl(act, grp + 24 + jj);
        float cn = fmaf(fv, cc[l], iv * gv);
        cc[l] = cn;
        float th = fmaf(2.0f, frcp(1.0f + fexp2(-2.885390082f * cn)), -1.0f);
        float hn = ov * th;
#pragma unroll
        for (int k = 0; k < 8; ++k) hrep[l][k] = __shfl(hn, grp + k);
      }
      xrow += DD;
    }
  }
  float pred = linB[0];
#pragma unroll
  for (int k = 0; k < 8; ++k) pred = fmaf(linW[k], hrep[2][k], pred);
  if (g == 0) out[e] = pred;
}

extern "C" void kernel_launch(void* const* d_in, const int* in_sizes, int n_in,
                              void* d_out, int out_size, void* d_ws, size_t ws_size,
                              hipStream_t stream) {
  const float* x     = (const float*)d_in[0];
  const float* h0    = (const float*)d_in[1];
  const float* c0    = (const float*)d_in[2];
  const float* eWih0 = (const float*)d_in[3];
  const float* eWihR = (const float*)d_in[4];
  const float* eWhh  = (const float*)d_in[5];
  const float* eBih  = (const float*)d_in[6];
  const float* eBhh  = (const float*)d_in[7];
  const float* dWih0 = (const float*)d_in[8];
  const float* dWihR = (const float*)d_in[9];
  const float* dWhh  = (const float*)d_in[10];
  const float* dBih  = (const float*)d_in[11];
  const float* dBhh  = (const float*)d_in[12];
  const float* linW  = (const float*)d_in[13];
  const float* linB  = (const float*)d_in[14];
  float* out = (float*)d_out;

  const size_t P_BYTES = (size_t)2 * BB * TT * 32 * sizeof(float);  // 128 MiB
  if (ws_size >= P_BYTES) {
    float* P = (float*)d_ws;
    proj_kernel<<<2048, 256, 0, stream>>>(x, eWih0, eBih, eBhh, dWih0, dBih, dBhh, P);
    recur_kernel<<<BB / 4, 64, 0, stream>>>(P, h0, c0, eWihR, eWhh, eBih, eBhh,
                                            dWihR, dWhh, dBih, dBhh, linW, linB, out);
  } else {
    seq2seq_fallback<<<BB / 2, 64, 0, stream>>>(x, h0, c0, eWih0, eWihR, eWhh, eBih, eBhh,
                                                dWih0, dWihR, dWhh, dBih, dBhh, linW, linB, out);
  }
}

// Round 2
// 651.770 us; speedup vs baseline: 1.1979x; 1.1979x over previous
//
#include <hip/hip_runtime.h>

#define TT 512
#define DD 64
#define BB 1024
#define PF 8               // prefetch depth (steps) in the recurrence
#define HH 8

typedef float v2f __attribute__((ext_vector_type(2)));

__device__ __forceinline__ float fexp2(float x){ return __builtin_amdgcn_exp2f(x); }
__device__ __forceinline__ float frcp (float x){ return __builtin_amdgcn_rcpf(x); }

__device__ __forceinline__ v2f bc2(float s){ v2f r; r.x = s; r.y = s; return r; }

#if defined(__has_builtin)
#if __has_builtin(__builtin_elementwise_fma)
#define HAVE_EW_FMA 1
#endif
#endif

__device__ __forceinline__ v2f vfma(v2f a, v2f b, v2f c){
#ifdef HAVE_EW_FMA
  return __builtin_elementwise_fma(a, b, c);
#else
  v2f r; r.x = fmaf(a.x, b.x, c.x); r.y = fmaf(a.y, b.y, c.y); return r;
#endif
}

// DPP: quad_perm uniform selectors (direction-proof) and row_ror:4k whose
// direction is resolved by a runtime probe.
template<int C>
__device__ __forceinline__ float dppf(float x){
  return __int_as_float(__builtin_amdgcn_update_dpp(0, __float_as_int(x), C, 0xF, 0xF, true));
}
template<int C>
__device__ __forceinline__ int dppi(int x){
  return __builtin_amdgcn_update_dpp(0, x, C, 0xF, 0xF, true);
}

// ============================================================
// Kernel 1 (v2 — REVERTED to verified LDS-broadcast version):
// layer-0 input projection for both phases.
// P[ph][e][t][32], pos(r) = (gate*4 + (j&3))*2 + (j>>2), value includes bias.
// 2048 blocks x 256 threads. Each wave owns 64 consecutive x-rows, processed
// as 4 groups of 16 rows through a wave-private double-buffered LDS tile.
// ============================================================
__global__ __launch_bounds__(256) void proj_kernel(
    const float* __restrict__ x,
    const float* __restrict__ eWih0, const float* __restrict__ eBih, const float* __restrict__ eBhh,
    const float* __restrict__ dWih0, const float* __restrict__ dBih, const float* __restrict__ dBhh,
    float* __restrict__ P)
{
  __shared__ __align__(16) float xs[4][2][16 * 64];   // [wave][buf][row*64+k] = 32 KiB
  const int tid  = threadIdx.x;
  const int w    = tid >> 6;
  const int lane = tid & 63;
  const int ph   = lane >> 5;
  const int r    = lane & 31;
  const float* W = ph ? dWih0 : eWih0;
  const float b0 = ph ? (dBih[r] + dBhh[r]) : (eBih[r] + eBhh[r]);
  const int gate = r >> 3, j = r & 7;
  const int pos  = (gate * 4 + (j & 3)) * 2 + (j >> 2);

  float Wx[64];
#pragma unroll
  for (int k = 0; k < 16; ++k) {
    float4 wq = *(const float4*)(W + r * 64 + k * 4);
    Wx[k*4+0] = wq.x; Wx[k*4+1] = wq.y; Wx[k*4+2] = wq.z; Wx[k*4+3] = wq.w;
  }

  const int base_row = (blockIdx.x * 4 + w) * 64;     // 8192 waves x 64 rows
  const float* xg = x + (size_t)base_row * 64;

  float4 st[4];
  // stage group 0 into buf 0
#pragma unroll
  for (int i = 0; i < 4; ++i) st[i] = *(const float4*)(xg + i * 256 + lane * 4);
#pragma unroll
  for (int i = 0; i < 4; ++i) *(float4*)&xs[w][0][i * 256 + lane * 4] = st[i];
  // issue loads for group 1
#pragma unroll
  for (int i = 0; i < 4; ++i) st[i] = *(const float4*)(xg + 1024 + i * 256 + lane * 4);

#pragma unroll 1
  for (int g = 0; g < 4; ++g) {
    const float* buf = &xs[w][g & 1][0];
#pragma unroll 2
    for (int ri = 0; ri < 16; ++ri) {
      float a0 = b0, a1 = 0.f, a2 = 0.f, a3 = 0.f;
#pragma unroll
      for (int kc = 0; kc < 16; ++kc) {
        float4 xv = *(const float4*)(buf + ri * 64 + kc * 4);
        a0 = fmaf(Wx[kc*4+0], xv.x, a0);
        a1 = fmaf(Wx[kc*4+1], xv.y, a1);
        a2 = fmaf(Wx[kc*4+2], xv.z, a2);
        a3 = fmaf(Wx[kc*4+3], xv.w, a3);
      }
      const int row = base_row + g * 16 + ri;
      const int e = row >> 9, t = row & 511;
      P[((size_t)((ph << 10) + e) * TT + t) * 32 + pos] = (a0 + a1) + (a2 + a3);
    }
    if (g < 3) {
      // commit staged group g+1 (waits vmcnt for st automatically)
#pragma unroll
      for (int i = 0; i < 4; ++i) *(float4*)&xs[w][(g + 1) & 1][i * 256 + lane * 4] = st[i];
      if (g < 2) {
        // issue loads for group g+2
#pragma unroll
        for (int i = 0; i < 4; ++i)
          st[i] = *(const float4*)(xg + (size_t)(g + 2) * 1024 + i * 256 + lane * 4);
      }
    }
  }
}

// ============================================================
// Kernel 2 (v2): layer-pipelined recurrence.
// 256 blocks x 192 threads = 3 waves/block, one LSTM LAYER per wave, running
// on 3 SIMDs of the same CU. Software-pipeline skew across waves:
//   interval k: wave0 does layer0 t=k, wave1 layer1 t=k-1, wave2 layer2 t=k-2.
// The below-dot accB (one v2f per lane, identical lane layout) is handed
// through double-buffered LDS slots; one __syncthreads per interval.
// Arithmetic sequences are IDENTICAL to the verified single-wave version
// (same FMA order, same data flow) -> bit-identical output.
// Lane layout per wave (unchanged): row=lane>>4 -> elem, L=lane&15,
// u=L>>2 unit-quad, g=L&3 torch gate; slot pair (u, u+4) packed in v2f.
// ============================================================
__global__ __launch_bounds__(192) void recur_kernel(
    const float* __restrict__ P,
    const float* __restrict__ h0,    const float* __restrict__ c0,
    const float* __restrict__ eWihR, const float* __restrict__ eWhh,
    const float* __restrict__ eBih,  const float* __restrict__ eBhh,
    const float* __restrict__ dWihR, const float* __restrict__ dWhh,
    const float* __restrict__ dBih,  const float* __restrict__ dBhh,
    const float* __restrict__ linW,  const float* __restrict__ linB,
    float* __restrict__ out)
{
  __shared__ v2f bufA[2][64];   // wave0 -> wave1 below-dots
  __shared__ v2f bufB[2][64];   // wave1 -> wave2 below-dots

  const int tid  = threadIdx.x;
  const int w    = tid >> 6;          // my layer (0,1,2)
  const int lane = tid & 63;
  const int row  = lane >> 4;
  const int L    = lane & 15;
  const int u    = L >> 2;
  const int g    = L & 3;
  const int e    = blockIdx.x * 4 + row;

  const bool is_tanh = (g == 2);
  const float ns_act = is_tanh ? -2.885390082f : -1.44269504f;
  const float a_act  = is_tanh ? 2.0f : 1.0f;
  const float b_act  = is_tanh ? -1.0f : 0.0f;

  const bool seedb = (w > 0);   // my layer's bias seeds my self-dot (l0 bias in P)
  const bool below = (w < 2);   // I produce the below-dot for layer w+1

  // runtime direction probe for row_ror:4 (wave-uniform d = 1 or 3)
  const int p4 = dppi<0x124>(u);
  const int d  = __builtin_amdgcn_readfirstlane((p4 - u) & 3);

  v2f Hm, cm, sdm;
  v2f WSm[8], WBm[8], Bsm = bc2(0.f);

  Hm.x = h0[((size_t)w * BB + e) * HH + u];
  Hm.y = h0[((size_t)w * BB + e) * HH + u + 4];
  cm.x = c0[((size_t)w * BB + e) * HH + u];
  cm.y = c0[((size_t)w * BB + e) * HH + u + 4];

  auto load_phase = [&](const float* WihR, const float* Whh,
                        const float* Bih, const float* Bhh) {
    const int r0 = w * 32 + g * 8 + u;
#pragma unroll
    for (int k = 0; k < 4; ++k) {
      const int col = (u + d * k) & 3;
      WSm[k].x     = Whh[r0 * 8 + col];
      WSm[k].y     = Whh[(r0 + 4) * 8 + col];
      WSm[4 + k].x = Whh[r0 * 8 + 4 + col];
      WSm[4 + k].y = Whh[(r0 + 4) * 8 + 4 + col];
    }
    if (below) {
      // WihR block w = input weights of layer w+1 (consumed by my accB)
#pragma unroll
      for (int k = 0; k < 4; ++k) {
        const int col = (u + d * k) & 3;
        WBm[k].x     = WihR[r0 * 8 + col];
        WBm[k].y     = WihR[(r0 + 4) * 8 + col];
        WBm[4 + k].x = WihR[r0 * 8 + 4 + col];
        WBm[4 + k].y = WihR[(r0 + 4) * 8 + 4 + col];
      }
    }
    if (seedb) {
      Bsm.x = Bih[w * 32 + g * 8 + u]     + Bhh[w * 32 + g * 8 + u];
      Bsm.y = Bih[w * 32 + g * 8 + u + 4] + Bhh[w * 32 + g * 8 + u + 4];
    }
    // initial self-dot from current h
    float A0[4], B0[4];
    A0[0] = Hm.x; A0[1] = dppf<0x124>(Hm.x); A0[2] = dppf<0x128>(Hm.x); A0[3] = dppf<0x12C>(Hm.x);
    B0[0] = Hm.y; B0[1] = dppf<0x124>(Hm.y); B0[2] = dppf<0x128>(Hm.y); B0[3] = dppf<0x12C>(Hm.y);
    v2f acc = seedb ? Bsm : bc2(0.f);
#pragma unroll
    for (int k = 0; k < 4; ++k) {
      acc = vfma(WSm[k],     bc2(A0[k]), acc);
      acc = vfma(WSm[4 + k], bc2(B0[k]), acc);
    }
    sdm = acc;
  };

  // one packed LSTM cell step for my layer; returns below-dot for layer w+1
  auto lstep = [&](v2f in) -> v2f {
    v2f pre = in + sdm;
    v2f ex; ex.x = fexp2(ns_act * pre.x); ex.y = fexp2(ns_act * pre.y);
    v2f rc; rc.x = frcp(1.f + ex.x);      rc.y = frcp(1.f + ex.y);
    v2f act = vfma(bc2(a_act), rc, bc2(b_act));
    v2f Gi, Gf, Gg, Go;
    Gi.x = dppf<0x00>(act.x); Gi.y = dppf<0x00>(act.y);
    Gf.x = dppf<0x55>(act.x); Gf.y = dppf<0x55>(act.y);
    Gg.x = dppf<0xAA>(act.x); Gg.y = dppf<0xAA>(act.y);
    Go.x = dppf<0xFF>(act.x); Go.y = dppf<0xFF>(act.y);
    v2f cn = vfma(Gf, cm, Gi * Gg);
    cm = cn;
    v2f tx; tx.x = fexp2(-2.885390082f * cn.x); tx.y = fexp2(-2.885390082f * cn.y);
    v2f tr; tr.x = frcp(1.f + tx.x);            tr.y = frcp(1.f + tx.y);
    v2f th = vfma(bc2(2.f), tr, bc2(-1.f));
    v2f hn = Go * th;
    Hm = hn;
    float A0[4], B0[4];
    A0[0] = hn.x; A0[1] = dppf<0x124>(hn.x); A0[2] = dppf<0x128>(hn.x); A0[3] = dppf<0x12C>(hn.x);
    B0[0] = hn.y; B0[1] = dppf<0x124>(hn.y); B0[2] = dppf<0x128>(hn.y); B0[3] = dppf<0x12C>(hn.y);
    v2f accS = seedb ? Bsm : bc2(0.f);
#pragma unroll
    for (int k = 0; k < 4; ++k) {
      accS = vfma(WSm[k],     bc2(A0[k]), accS);
      accS = vfma(WSm[4 + k], bc2(B0[k]), accS);
    }
    sdm = accS;
    v2f accB = bc2(0.f);
    if (below) {
#pragma unroll
      for (int k = 0; k < 4; ++k) {
        accB = vfma(WBm[k],     bc2(A0[k]), accB);
        accB = vfma(WBm[4 + k], bc2(B0[k]), accB);
      }
    }
    return accB;
  };

#pragma unroll 1
  for (int ph = 0; ph < 2; ++ph) {
    if (ph == 0) load_phase(eWihR, eWhh, eBih, eBhh);
    else         load_phase(dWihR, dWhh, dBih, dBhh);

    const float* Pb = P + ((size_t)((ph << 10) + e) * TT) * 32 + (g * 4 + u) * 2;

    v2f pf[PF];
    if (w == 0) {
#pragma unroll
      for (int k = 0; k < PF; ++k) pf[k] = *(const v2f*)(Pb + k * 32);
    }

    // main intervals k = 0..511; wave0: t=k, wave1: t=k-1, wave2: t=k-2
#pragma unroll 1
    for (int kb = 0; kb < TT; kb += PF) {
#pragma unroll
      for (int j = 0; j < PF; ++j) {
        const int k = kb + j;
        if (w == 0) {
          v2f cur = pf[j];
          int tn = k + PF; if (tn > TT - 1) tn = TT - 1;
          pf[j] = *(const v2f*)(Pb + tn * 32);
          v2f n1 = lstep(cur);
          bufA[j & 1][lane] = n1;              // slot k&1 == j&1 (kb even)
        } else if (w == 1) {
          if (k >= 1) {
            v2f i1 = bufA[(j ^ 1) & 1][lane];  // slot (k-1)&1
            v2f n2 = lstep(i1);
            bufB[(j ^ 1) & 1][lane] = n2;
          }
        } else {
          if (k >= 2) {
            v2f i2 = bufB[j & 1][lane];        // slot (k-2)&1
            (void)lstep(i2);
          }
        }
        __syncthreads();
      }
    }
    // drain interval k=512: wave1 t=511, wave2 t=510
    if (w == 1) {
      v2f i1 = bufA[1][lane];                  // t=511 written at k=511, slot 1
      v2f n2 = lstep(i1);
      bufB[1][lane] = n2;
    } else if (w == 2) {
      v2f i2 = bufB[0][lane];                  // t=510 written at k=511, slot 0
      (void)lstep(i2);
    }
    __syncthreads();
    // drain interval k=513: wave2 t=511
    if (w == 2) {
      v2f i2 = bufB[1][lane];
      (void)lstep(i2);
    }
    __syncthreads();
  }

  // epilogue: linear on final decoder layer-2 h (wave2 only)
  if (w == 2) {
    float lwA[4], lwB[4];
#pragma unroll
    for (int k = 0; k < 4; ++k) {
      const int col = (u + d * k) & 3;
      lwA[k] = linW[col];
      lwB[k] = linW[4 + col];
    }
    float A0[4], B0[4];
    A0[0] = Hm.x; A0[1] = dppf<0x124>(Hm.x); A0[2] = dppf<0x128>(Hm.x); A0[3] = dppf<0x12C>(Hm.x);
    B0[0] = Hm.y; B0[1] = dppf<0x124>(Hm.y); B0[2] = dppf<0x128>(Hm.y); B0[3] = dppf<0x12C>(Hm.y);
    float pred = linB[0];
#pragma unroll
    for (int k = 0; k < 4; ++k) {
      pred = fmaf(lwA[k], A0[k], pred);
      pred = fmaf(lwB[k], B0[k], pred);
    }
    if (L == 0) out[e] = pred;
  }
}

// ============================================================
// Fallback (ws too small): round-1 verified single-kernel version.
// ============================================================
__global__ __launch_bounds__(64) void seq2seq_fallback(
    const float* __restrict__ x, const float* __restrict__ h0, const float* __restrict__ c0,
    const float* __restrict__ eWih0, const float* __restrict__ eWihR, const float* __restrict__ eWhh,
    const float* __restrict__ eBih,  const float* __restrict__ eBhh,
    const float* __restrict__ dWih0, const float* __restrict__ dWihR, const float* __restrict__ dWhh,
    const float* __restrict__ dBih,  const float* __restrict__ dBhh,
    const float* __restrict__ linW,  const float* __restrict__ linB, float* __restrict__ out)
{
  const int tid = threadIdx.x;
  const int g   = tid & 31;
  const int grp = tid & 32;
  const int jj  = g & 7;
  const int e   = blockIdx.x * 2 + (tid >> 5);
  const bool is_tanh = ((g >> 3) == 2);
  const float s_act = is_tanh ? 2.885390082f : 1.44269504f;
  const float a_act = is_tanh ? 2.0f : 1.0f;
  const float b_act = is_tanh ? -1.0f : 0.0f;
  float hrep[3][8]; float cc[3];
#pragma unroll
  for (int l = 0; l < 3; ++l) {
#pragma unroll
    for (int k = 0; k < 8; ++k) hrep[l][k] = h0[((size_t)l * BB + e) * HH + k];
    cc[l] = c0[((size_t)l * BB + e) * HH + jj];
  }
  for (int p = 0; p < 2; ++p) {
    const float* Wih0 = p ? dWih0 : eWih0;  const float* WihR = p ? dWihR : eWihR;
    const float* Whh  = p ? dWhh  : eWhh;   const float* Bih  = p ? dBih  : eBih;
    const float* Bhh  = p ? dBhh  : eBhh;
    float Wx[64];
#pragma unroll
    for (int k = 0; k < 64; k += 4) {
      float4 w = *(const float4*)(Wih0 + g * 64 + k);
      Wx[k] = w.x; Wx[k+1] = w.y; Wx[k+2] = w.z; Wx[k+3] = w.w;
    }
    float Wh[3][8], Wi[2][8], bias[3];
#pragma unroll
    for (int l = 0; l < 3; ++l) {
#pragma unroll
      for (int k = 0; k < 8; ++k) Wh[l][k] = Whh[(l*32+g)*8+k];
      bias[l] = Bih[l*32+g] + Bhh[l*32+g];
    }
#pragma unroll
    for (int l = 0; l < 2; ++l)
#pragma unroll
      for (int k = 0; k < 8; ++k) Wi[l][k] = WihR[(l*32+g)*8+k];
    const float* xrow = x + (size_t)e * TT * DD;
    for (int t = 0; t < TT; ++t) {
      float4 acc = make_float4(bias[0], 0.f, 0.f, 0.f);
#pragma unroll
      for (int kc = 0; kc < 16; ++kc) {
        float4 xv = *(const float4*)(xrow + kc * 4);
        acc.x = fmaf(Wx[kc*4+0], xv.x, acc.x); acc.y = fmaf(Wx[kc*4+1], xv.y, acc.y);
        acc.z = fmaf(Wx[kc*4+2], xv.z, acc.z); acc.w = fmaf(Wx[kc*4+3], xv.w, acc.w);
      }
      float pre = (acc.x + acc.y) + (acc.z + acc.w);
      { float r0=0.f,r1=0.f;
#pragma unroll
        for (int k = 0; k < 8; k += 2) { r0=fmaf(Wh[0][k],hrep[0][k],r0); r1=fmaf(Wh[0][k+1],hrep[0][k+1],r1); }
        pre += r0 + r1; }
#pragma unroll
      for (int l = 0; l < 3; ++l) {
        if (l > 0) {
          float r0 = bias[l], r1 = 0.f;
#pragma unroll
          for (int k = 0; k < 8; k += 2) {
            r0=fmaf(Wi[l-1][k],hrep[l-1][k],r0); r1=fmaf(Wi[l-1][k+1],hrep[l-1][k+1],r1);
            r0=fmaf(Wh[l][k],hrep[l][k],r0);     r1=fmaf(Wh[l][k+1],hrep[l][k+1],r1);
          }
          pre = r0 + r1;
        }
        float act = fmaf(a_act, frcp(1.0f + fexp2(-s_act * pre)), b_act);
        float iv = __shfl(act, grp + jj);
        float fv = __shfl(act, grp + 8 + jj);
        float gv = __shfl(act, grp + 16 + jj);
        float ov = __shfl(act, grp + 24 + jj);
        float cn = fmaf(fv, cc[l], iv * gv);
        cc[l] = cn;
        float th = fmaf(2.0f, frcp(1.0f + fexp2(-2.885390082f * cn)), -1.0f);
        float hn = ov * th;
#pragma unroll
        for (int k = 0; k < 8; ++k) hrep[l][k] = __shfl(hn, grp + k);
      }
      xrow += DD;
    }
  }
  float pred = linB[0];
#pragma unroll
  for (int k = 0; k < 8; ++k) pred = fmaf(linW[k], hrep[2][k], pred);
  if (g == 0) out[e] = pred;
}

extern "C" void kernel_launch(void* const* d_in, const int* in_sizes, int n_in,
                              void* d_out, int out_size, void* d_ws, size_t ws_size,
                              hipStream_t stream) {
  const float* x     = (const float*)d_in[0];
  const float* h0    = (const float*)d_in[1];
  const float* c0    = (const float*)d_in[2];
  const float* eWih0 = (const float*)d_in[3];
  const float* eWihR = (const float*)d_in[4];
  const float* eWhh  = (const float*)d_in[5];
  const float* eBih  = (const float*)d_in[6];
  const float* eBhh  = (const float*)d_in[7];
  const float* dWih0 = (const float*)d_in[8];
  const float* dWihR = (const float*)d_in[9];
  const float* dWhh  = (const float*)d_in[10];
  const float* dBih  = (const float*)d_in[11];
  const float* dBhh  = (const float*)d_in[12];
  const float* linW  = (const float*)d_in[13];
  const float* linB  = (const float*)d_in[14];
  float* out = (float*)d_out;

  const size_t P_BYTES = (size_t)2 * BB * TT * 32 * sizeof(float);  // 128 MiB
  if (ws_size >= P_BYTES) {
    float* P = (float*)d_ws;
    proj_kernel<<<2048, 256, 0, stream>>>(x, eWih0, eBih, eBhh, dWih0, dBih, dBhh, P);
    recur_kernel<<<BB / 4, 192, 0, stream>>>(P, h0, c0, eWihR, eWhh, eBih, eBhh,
                                             dWihR, dWhh, dBih, dBhh, linW, linB, out);
  } else {
    seq2seq_fallback<<<BB / 2, 64, 0, stream>>>(x, h0, c0, eWih0, eWihR, eWhh, eBih, eBhh,
                                                dWih0, dWihR, dWhh, dBih, dBhh, linW, linB, out);
  }
}

// Round 3
// 607.148 us; speedup vs baseline: 1.2859x; 1.0735x over previous
//
#include <hip/hip_runtime.h>

#define TT 512
#define DD 64
#define BB 1024
#define PF 8               // prefetch depth (steps) in the recurrence
#define HH 8

typedef float v2f __attribute__((ext_vector_type(2)));

__device__ __forceinline__ float fexp2(float x){ return __builtin_amdgcn_exp2f(x); }
__device__ __forceinline__ float frcp (float x){ return __builtin_amdgcn_rcpf(x); }

// DPP: quad_perm uniform selectors (direction-proof) and row_ror:4k whose
// direction is resolved by a runtime probe.
template<int C>
__device__ __forceinline__ float dppf(float x){
  return __int_as_float(__builtin_amdgcn_update_dpp(0, __float_as_int(x), C, 0xF, 0xF, true));
}
template<int C>
__device__ __forceinline__ int dppi(int x){
  return __builtin_amdgcn_update_dpp(0, x, C, 0xF, 0xF, true);
}

// lane^16 exchange within each 32-lane group (BitMode: and=0x1F, or=0, xor=0x10)
__device__ __forceinline__ float swz16(float x){
  return __int_as_float(__builtin_amdgcn_ds_swizzle(__float_as_int(x), 0x401F));
}

template<int N> struct IC { static constexpr int v = N; };

// ============================================================
// Kernel 1 (v2 — verified): layer-0 input projection for both phases.
// P[ph][e][t][32], pos(r) = (gate*4 + (j&3))*2 + (j>>2), value includes bias.
// 2048 blocks x 256 threads. Each wave owns 64 consecutive x-rows, processed
// as 4 groups of 16 rows through a wave-private double-buffered LDS tile.
// ============================================================
__global__ __launch_bounds__(256) void proj_kernel(
    const float* __restrict__ x,
    const float* __restrict__ eWih0, const float* __restrict__ eBih, const float* __restrict__ eBhh,
    const float* __restrict__ dWih0, const float* __restrict__ dBih, const float* __restrict__ dBhh,
    float* __restrict__ P)
{
  __shared__ __align__(16) float xs[4][2][16 * 64];   // [wave][buf][row*64+k] = 32 KiB
  const int tid  = threadIdx.x;
  const int w    = tid >> 6;
  const int lane = tid & 63;
  const int ph   = lane >> 5;
  const int r    = lane & 31;
  const float* W = ph ? dWih0 : eWih0;
  const float b0 = ph ? (dBih[r] + dBhh[r]) : (eBih[r] + eBhh[r]);
  const int gate = r >> 3, j = r & 7;
  const int pos  = (gate * 4 + (j & 3)) * 2 + (j >> 2);

  float Wx[64];
#pragma unroll
  for (int k = 0; k < 16; ++k) {
    float4 wq = *(const float4*)(W + r * 64 + k * 4);
    Wx[k*4+0] = wq.x; Wx[k*4+1] = wq.y; Wx[k*4+2] = wq.z; Wx[k*4+3] = wq.w;
  }

  const int base_row = (blockIdx.x * 4 + w) * 64;     // 8192 waves x 64 rows
  const float* xg = x + (size_t)base_row * 64;

  float4 st[4];
  // stage group 0 into buf 0
#pragma unroll
  for (int i = 0; i < 4; ++i) st[i] = *(const float4*)(xg + i * 256 + lane * 4);
#pragma unroll
  for (int i = 0; i < 4; ++i) *(float4*)&xs[w][0][i * 256 + lane * 4] = st[i];
  // issue loads for group 1
#pragma unroll
  for (int i = 0; i < 4; ++i) st[i] = *(const float4*)(xg + 1024 + i * 256 + lane * 4);

#pragma unroll 1
  for (int g = 0; g < 4; ++g) {
    const float* buf = &xs[w][g & 1][0];
#pragma unroll 2
    for (int ri = 0; ri < 16; ++ri) {
      float a0 = b0, a1 = 0.f, a2 = 0.f, a3 = 0.f;
#pragma unroll
      for (int kc = 0; kc < 16; ++kc) {
        float4 xv = *(const float4*)(buf + ri * 64 + kc * 4);
        a0 = fmaf(Wx[kc*4+0], xv.x, a0);
        a1 = fmaf(Wx[kc*4+1], xv.y, a1);
        a2 = fmaf(Wx[kc*4+2], xv.z, a2);
        a3 = fmaf(Wx[kc*4+3], xv.w, a3);
      }
      const int row = base_row + g * 16 + ri;
      const int e = row >> 9, t = row & 511;
      P[((size_t)((ph << 10) + e) * TT + t) * 32 + pos] = (a0 + a1) + (a2 + a3);
    }
    if (g < 3) {
      // commit staged group g+1 (waits vmcnt for st automatically)
#pragma unroll
      for (int i = 0; i < 4; ++i) *(float4*)&xs[w][(g + 1) & 1][i * 256 + lane * 4] = st[i];
      if (g < 2) {
        // issue loads for group g+2
#pragma unroll
        for (int i = 0; i < 4; ++i)
          st[i] = *(const float4*)(xg + (size_t)(g + 2) * 1024 + i * 256 + lane * 4);
      }
    }
  }
}

// ============================================================
// Kernel 2 (v3): scalar-lane recurrence, 1 output per lane.
// 256 blocks x 128 threads = 512 waves = 2 waves/CU (2 SIMDs busy).
// Each elem uses 32 lanes: unit v = (idx>>2) in 0..7, gate g = idx&3.
// Units 0-3 live in DPP row 0, units 4-7 in row 1 of each 32-lane half.
// h-broadcast: low-h via row_ror:4k DPP (as verified), cross-row h via one
// ds_swizzle lane^16 + 2 cndmask (Lo/Hi). Dot order, W-col rotation
// (b+d*k)&3 with runtime d-probe, activation math, PF=8 prefetch, and the
// layer skew (bd1/bd2) replicate the verified kernel EXACTLY -> absmax 0.0.
// No LDS buffers, no barriers; waves fully independent.
// ============================================================
__global__ __launch_bounds__(128) void recur_kernel(
    const float* __restrict__ P,
    const float* __restrict__ h0,    const float* __restrict__ c0,
    const float* __restrict__ eWihR, const float* __restrict__ eWhh,
    const float* __restrict__ eBih,  const float* __restrict__ eBhh,
    const float* __restrict__ dWihR, const float* __restrict__ dWhh,
    const float* __restrict__ dBih,  const float* __restrict__ dBhh,
    const float* __restrict__ linW,  const float* __restrict__ linB,
    float* __restrict__ out)
{
  const int tid = threadIdx.x;
  const int idx = tid & 31;          // within-elem lane
  const int v   = idx >> 2;          // unit 0..7
  const int g   = idx & 3;           // torch gate (i,f,g,o)
  const int b   = v & 3;             // rotation base (low-col index)
  const bool rB = (v >= 4);          // DPP row-1 lanes
  const int e   = blockIdx.x * 4 + (tid >> 5);

  const bool is_tanh = (g == 2);
  const float ns_act = is_tanh ? -2.885390082f : -1.44269504f;
  const float a_act  = is_tanh ? 2.0f : 1.0f;
  const float b_act  = is_tanh ? -1.0f : 0.0f;

  // runtime direction probe for row_ror:4 (wave-uniform d = 1 or 3),
  // identical operand pattern to the verified kernel
  const int qidx = (tid >> 2) & 3;
  const int p4 = dppi<0x124>(qidx);
  const int d  = __builtin_amdgcn_readfirstlane((p4 - qidx) & 3);

  float H[3], cs[3], sd[3];
  float bd1 = 0.f, bd2 = 0.f;
  float WS[3][8], WB[2][8], Bss[2];

#pragma unroll
  for (int l = 0; l < 3; ++l) {
    H[l]  = h0[((size_t)l * BB + e) * HH + v];
    cs[l] = c0[((size_t)l * BB + e) * HH + v];
  }

  // broadcast h[0..7] of my elem into A[4] (low h's) / Bv[4] (high h's),
  // in the verified rotation order: A[k] = h[(b+d*k)&3], Bv[k] = h[4+((b+d*k)&3)]
  auto bcast = [&](float hn, float* A, float* Bv) {
    float Hsw = swz16(hn);             // other row's h at my within-row quad
    float Lo = rB ? Hsw : hn;          // h[q] at within-row quad q (all lanes)
    float Hi = rB ? hn : Hsw;          // h[4+q] at within-row quad q
    A[0]  = Lo; A[1]  = dppf<0x124>(Lo); A[2]  = dppf<0x128>(Lo); A[3]  = dppf<0x12C>(Lo);
    Bv[0] = Hi; Bv[1] = dppf<0x124>(Hi); Bv[2] = dppf<0x128>(Hi); Bv[3] = dppf<0x12C>(Hi);
  };

  auto load_phase = [&](const float* WihR, const float* Whh,
                        const float* Bih, const float* Bhh) {
#pragma unroll
    for (int l = 0; l < 3; ++l) {
      const int r0 = l * 32 + g * 8 + v;
#pragma unroll
      for (int k = 0; k < 4; ++k) {
        const int col = (b + d * k) & 3;
        WS[l][k]     = Whh[r0 * 8 + col];
        WS[l][4 + k] = Whh[r0 * 8 + 4 + col];
      }
    }
#pragma unroll
    for (int l = 0; l < 2; ++l) {
      const int r0 = l * 32 + g * 8 + v;
#pragma unroll
      for (int k = 0; k < 4; ++k) {
        const int col = (b + d * k) & 3;
        WB[l][k]     = WihR[r0 * 8 + col];
        WB[l][4 + k] = WihR[r0 * 8 + 4 + col];
      }
      Bss[l] = Bih[(l + 1) * 32 + g * 8 + v] + Bhh[(l + 1) * 32 + g * 8 + v];
    }
    // self-dots from current h (layer-0 bias lives inside P)
#pragma unroll
    for (int l = 0; l < 3; ++l) {
      float A[4], Bv[4];
      bcast(H[l], A, Bv);
      float acc = l ? Bss[l - 1] : 0.f;
#pragma unroll
      for (int k = 0; k < 4; ++k) {
        acc = fmaf(WS[l][k],     A[k],  acc);
        acc = fmaf(WS[l][4 + k], Bv[k], acc);
      }
      sd[l] = acc;
    }
  };

  // one scalar LSTM cell step for layer l; returns below-dot for layer l+1
  auto lstep = [&](auto LC, float in) -> float {
    constexpr int l = decltype(LC)::v;
    float pre = in + sd[l];
    float ex  = fexp2(ns_act * pre);
    float rc  = frcp(1.f + ex);
    float act = fmaf(a_act, rc, b_act);
    float Gi = dppf<0x00>(act);
    float Gf = dppf<0x55>(act);
    float Gg = dppf<0xAA>(act);
    float Go = dppf<0xFF>(act);
    float cn = fmaf(Gf, cs[l], Gi * Gg);
    cs[l] = cn;
    float tx = fexp2(-2.885390082f * cn);
    float tr = frcp(1.f + tx);
    float th = fmaf(2.f, tr, -1.f);
    float hn = Go * th;
    H[l] = hn;
    float A[4], Bv[4];
    bcast(hn, A, Bv);
    float accS;
    if constexpr (l > 0) accS = Bss[l - 1]; else accS = 0.f;
#pragma unroll
    for (int k = 0; k < 4; ++k) {
      accS = fmaf(WS[l][k],     A[k],  accS);
      accS = fmaf(WS[l][4 + k], Bv[k], accS);
    }
    sd[l] = accS;
    float accB = 0.f;
    if constexpr (l < 2) {
#pragma unroll
      for (int k = 0; k < 4; ++k) {
        accB = fmaf(WB[l][k],     A[k],  accB);
        accB = fmaf(WB[l][4 + k], Bv[k], accB);
      }
    }
    return accB;
  };

#pragma unroll 1
  for (int ph = 0; ph < 2; ++ph) {
    if (ph == 0) load_phase(eWihR, eWhh, eBih, eBhh);
    else         load_phase(dWihR, dWhh, dBih, dBhh);

    const int pos = (g * 4 + b) * 2 + (v >> 2);
    const float* Pb = P + ((size_t)((ph << 10) + e) * TT) * 32 + pos;

    // fill prefetch pipeline with steps 0..PF-1
    float pf[PF];
#pragma unroll
    for (int k = 0; k < PF; ++k) pf[k] = Pb[k * 32];

    // peeled group t = 0..7 (skew startup), refill t = 8..15
#pragma unroll
    for (int k = 0; k < PF; ++k) {
      float cur = pf[k];
      pf[k] = Pb[(k + PF) * 32];
      float n1 = lstep(IC<0>{}, cur);
      float n2 = 0.f;
      if (k >= 1) n2 = lstep(IC<1>{}, bd1);
      if (k >= 2) (void)lstep(IC<2>{}, bd2);
      bd1 = n1; bd2 = n2;
    }

    // main loop t = 8..511, branch-free
#pragma unroll 1
    for (int t = PF; t < TT; t += PF) {
#pragma unroll
      for (int k = 0; k < PF; ++k) {
        float cur = pf[k];
        int tn = t + k + PF; if (tn > TT - 1) tn = TT - 1;
        pf[k] = Pb[(size_t)tn * 32];
        float n1 = lstep(IC<0>{}, cur);
        float n2 = lstep(IC<1>{}, bd1);
        (void)lstep(IC<2>{}, bd2);
        bd1 = n1; bd2 = n2;
      }
    }

    // drain skew: layer1 t=511, layer2 t=510, layer2 t=511
    float dd = lstep(IC<1>{}, bd1);
    (void)lstep(IC<2>{}, bd2);
    (void)lstep(IC<2>{}, dd);
  }

  // epilogue: linear on final decoder layer-2 h
  float lwA[4], lwB[4];
#pragma unroll
  for (int k = 0; k < 4; ++k) {
    const int col = (b + d * k) & 3;
    lwA[k] = linW[col];
    lwB[k] = linW[4 + col];
  }
  float A[4], Bv[4];
  bcast(H[2], A, Bv);
  float pred = linB[0];
#pragma unroll
  for (int k = 0; k < 4; ++k) {
    pred = fmaf(lwA[k], A[k],  pred);
    pred = fmaf(lwB[k], Bv[k], pred);
  }
  if (idx == 0) out[e] = pred;
}

// ============================================================
// Fallback (ws too small): round-1 verified single-kernel version.
// ============================================================
__global__ __launch_bounds__(64) void seq2seq_fallback(
    const float* __restrict__ x, const float* __restrict__ h0, const float* __restrict__ c0,
    const float* __restrict__ eWih0, const float* __restrict__ eWihR, const float* __restrict__ eWhh,
    const float* __restrict__ eBih,  const float* __restrict__ eBhh,
    const float* __restrict__ dWih0, const float* __restrict__ dWihR, const float* __restrict__ dWhh,
    const float* __restrict__ dBih,  const float* __restrict__ dBhh,
    const float* __restrict__ linW,  const float* __restrict__ linB, float* __restrict__ out)
{
  const int tid = threadIdx.x;
  const int g   = tid & 31;
  const int grp = tid & 32;
  const int jj  = g & 7;
  const int e   = blockIdx.x * 2 + (tid >> 5);
  const bool is_tanh = ((g >> 3) == 2);
  const float s_act = is_tanh ? 2.885390082f : 1.44269504f;
  const float a_act = is_tanh ? 2.0f : 1.0f;
  const float b_act = is_tanh ? -1.0f : 0.0f;
  float hrep[3][8]; float cc[3];
#pragma unroll
  for (int l = 0; l < 3; ++l) {
#pragma unroll
    for (int k = 0; k < 8; ++k) hrep[l][k] = h0[((size_t)l * BB + e) * HH + k];
    cc[l] = c0[((size_t)l * BB + e) * HH + jj];
  }
  for (int p = 0; p < 2; ++p) {
    const float* Wih0 = p ? dWih0 : eWih0;  const float* WihR = p ? dWihR : eWihR;
    const float* Whh  = p ? dWhh  : eWhh;   const float* Bih  = p ? dBih  : eBih;
    const float* Bhh  = p ? dBhh  : eBhh;
    float Wx[64];
#pragma unroll
    for (int k = 0; k < 64; k += 4) {
      float4 w = *(const float4*)(Wih0 + g * 64 + k);
      Wx[k] = w.x; Wx[k+1] = w.y; Wx[k+2] = w.z; Wx[k+3] = w.w;
    }
    float Wh[3][8], Wi[2][8], bias[3];
#pragma unroll
    for (int l = 0; l < 3; ++l) {
#pragma unroll
      for (int k = 0; k < 8; ++k) Wh[l][k] = Whh[(l*32+g)*8+k];
      bias[l] = Bih[l*32+g] + Bhh[l*32+g];
    }
#pragma unroll
    for (int l = 0; l < 2; ++l)
#pragma unroll
      for (int k = 0; k < 8; ++k) Wi[l][k] = WihR[(l*32+g)*8+k];
    const float* xrow = x + (size_t)e * TT * DD;
    for (int t = 0; t < TT; ++t) {
      float4 acc = make_float4(bias[0], 0.f, 0.f, 0.f);
#pragma unroll
      for (int kc = 0; kc < 16; ++kc) {
        float4 xv = *(const float4*)(xrow + kc * 4);
        acc.x = fmaf(Wx[kc*4+0], xv.x, acc.x); acc.y = fmaf(Wx[kc*4+1], xv.y, acc.y);
        acc.z = fmaf(Wx[kc*4+2], xv.z, acc.z); acc.w = fmaf(Wx[kc*4+3], xv.w, acc.w);
      }
      float pre = (acc.x + acc.y) + (acc.z + acc.w);
      { float r0=0.f,r1=0.f;
#pragma unroll
        for (int k = 0; k < 8; k += 2) { r0=fmaf(Wh[0][k],hrep[0][k],r0); r1=fmaf(Wh[0][k+1],hrep[0][k+1],r1); }
        pre += r0 + r1; }
#pragma unroll
      for (int l = 0; l < 3; ++l) {
        if (l > 0) {
          float r0 = bias[l], r1 = 0.f;
#pragma unroll
          for (int k = 0; k < 8; k += 2) {
            r0=fmaf(Wi[l-1][k],hrep[l-1][k],r0); r1=fmaf(Wi[l-1][k+1],hrep[l-1][k+1],r1);
            r0=fmaf(Wh[l][k],hrep[l][k],r0);     r1=fmaf(Wh[l][k+1],hrep[l][k+1],r1);
          }
          pre = r0 + r1;
        }
        float act = fmaf(a_act, frcp(1.0f + fexp2(-s_act * pre)), b_act);
        float iv = __shfl(act, grp + jj);
        float fv = __shfl(act, grp + 8 + jj);
        float gv = __shfl(act, grp + 16 + jj);
        float ov = __shfl(act, grp + 24 + jj);
        float cn = fmaf(fv, cc[l], iv * gv);
        cc[l] = cn;
        float th = fmaf(2.0f, frcp(1.0f + fexp2(-2.885390082f * cn)), -1.0f);
        float hn = ov * th;
#pragma unroll
        for (int k = 0; k < 8; ++k) hrep[l][k] = __shfl(hn, grp + k);
      }
      xrow += DD;
    }
  }
  float pred = linB[0];
#pragma unroll
  for (int k = 0; k < 8; ++k) pred = fmaf(linW[k], hrep[2][k], pred);
  if (g == 0) out[e] = pred;
}

extern "C" void kernel_launch(void* const* d_in, const int* in_sizes, int n_in,
                              void* d_out, int out_size, void* d_ws, size_t ws_size,
                              hipStream_t stream) {
  const float* x     = (const float*)d_in[0];
  const float* h0    = (const float*)d_in[1];
  const float* c0    = (const float*)d_in[2];
  const float* eWih0 = (const float*)d_in[3];
  const float* eWihR = (const float*)d_in[4];
  const float* eWhh  = (const float*)d_in[5];
  const float* eBih  = (const float*)d_in[6];
  const float* eBhh  = (const float*)d_in[7];
  const float* dWih0 = (const float*)d_in[8];
  const float* dWihR = (const float*)d_in[9];
  const float* dWhh  = (const float*)d_in[10];
  const float* dBih  = (const float*)d_in[11];
  const float* dBhh  = (const float*)d_in[12];
  const float* linW  = (const float*)d_in[13];
  const float* linB  = (const float*)d_in[14];
  float* out = (float*)d_out;

  const size_t P_BYTES = (size_t)2 * BB * TT * 32 * sizeof(float);  // 128 MiB
  if (ws_size >= P_BYTES) {
    float* P = (float*)d_ws;
    proj_kernel<<<2048, 256, 0, stream>>>(x, eWih0, eBih, eBhh, dWih0, dBih, dBhh, P);
    recur_kernel<<<BB / 4, 128, 0, stream>>>(P, h0, c0, eWihR, eWhh, eBih, eBhh,
                                             dWihR, dWhh, dBih, dBhh, linW, linB, out);
  } else {
    seq2seq_fallback<<<BB / 2, 64, 0, stream>>>(x, h0, c0, eWih0, eWihR, eWhh, eBih, eBhh,
                                                dWih0, dWihR, dWhh, dBih, dBhh, linW, linB, out);
  }
}